// Round 5
// baseline (1243.502 us; speedup 1.0000x reference)
//
#include <hip/hip_runtime.h>
#include <stdint.h>
#include <math.h>

#define B_    2048
#define DIN_  512
#define H_    768
#define A_    5001
#define APAD_ 5120
#define RL_   4
#define NDATA_ 56000.0f

typedef _Float16 f16x8 __attribute__((ext_vector_type(8)));
typedef _Float16 f16x4 __attribute__((ext_vector_type(4)));
typedef float    f32x4 __attribute__((ext_vector_type(4)));

// ---------------- threefry2x32 (exact JAX semantics) ----------------
__host__ __device__ __forceinline__ void threefry2x32(
    uint32_t k0, uint32_t k1, uint32_t x0, uint32_t x1,
    uint32_t* o0, uint32_t* o1)
{
  const uint32_t ks2 = k0 ^ k1 ^ 0x1BD11BDAu;
#define TF_R(r) { x0 += x1; x1 = (x1 << (r)) | (x1 >> (32 - (r))); x1 ^= x0; }
  x0 += k0; x1 += k1;
  TF_R(13) TF_R(15) TF_R(26) TF_R(6)
  x0 += k1;  x1 += ks2 + 1u;
  TF_R(17) TF_R(29) TF_R(16) TF_R(24)
  x0 += ks2; x1 += k0 + 2u;
  TF_R(13) TF_R(15) TF_R(26) TF_R(6)
  x0 += k0;  x1 += k1 + 3u;
  TF_R(17) TF_R(29) TF_R(16) TF_R(24)
  x0 += k1;  x1 += ks2 + 4u;
  TF_R(13) TF_R(15) TF_R(26) TF_R(6)
  x0 += ks2; x1 += k0 + 5u;
#undef TF_R
  *o0 = x0; *o1 = x1;
}

__device__ __forceinline__ float gumbel_for(uint32_t k0, uint32_t k1, uint32_t n)
{
  uint32_t o0, o1;
  threefry2x32(k0, k1, 0u, n, &o0, &o1);
  const uint32_t bits = o0 ^ o1;
  const float f = __uint_as_float((bits >> 9) | 0x3f800000u);  // [1,2)
  const float minv = 1e-6f;
  const float maxv = 1.0f - 1e-6f;
  const float span = maxv - minv;
  float u = __fmul_rn(f, span);
  u = __fadd_rn(u, minv);
  u = __fsub_rn(u, span);
  u = fmaxf(minv, u);
  return -logf(-logf(u));
}

// split v*64 into f16 hi/lo
struct HL { _Float16 h, l; };
__device__ __forceinline__ HL split64(float v)
{
  HL r;
  const float s = v * 64.f;
  r.h = (_Float16)s;
  r.l = (_Float16)(s - (float)r.h);
  return r;
}

// async global->LDS, 16 B per lane; LDS dst = base + lane*16 (wave-uniform base)
__device__ __forceinline__ void gload16(const void* g, void* l)
{
  __builtin_amdgcn_global_load_lds(
      (const __attribute__((address_space(1))) void*)g,
      (__attribute__((address_space(3))) void*)l, 16, 0, 0);
}

// ---------------- merged pre-split of all 6 weight tensors ----------------
struct PSJobs {
  const float* src[6];
  _Float16* hi[6];
  _Float16* lo[6];
  int R[6]; int K[6];
  int cum[7];          // cumulative float4 counts
};

__global__ __launch_bounds__(256)
void presplit_all(PSJobs J)
{
  const int g = blockIdx.x * 256 + threadIdx.x;
  if (g >= J.cum[6]) return;
  int j = 0;
  while (g >= J.cum[j + 1]) ++j;
  const int i = g - J.cum[j];
  const int K = J.K[j];
  const int e = i * 4;
  const int row = e / K;
  float4 f = make_float4(0.f, 0.f, 0.f, 0.f);
  if (row < J.R[j]) f = *(const float4*)(J.src[j] + (size_t)row * K + (e - row * K));
  const HL s0 = split64(f.x), s1 = split64(f.y);
  const HL s2 = split64(f.z), s3 = split64(f.w);
  const f16x4 hv = {s0.h, s1.h, s2.h, s3.h};
  ((f16x4*)J.hi[j])[i] = hv;
  if (J.lo[j]) {
    const f16x4 lv = {s0.l, s1.l, s2.l, s3.l};
    ((f16x4*)J.lo[j])[i] = lv;
  }
}

// ---------------- max ||Wh_a||^2 (for the refine bound) ----------------
__global__ __launch_bounds__(256)
void wmax_k(const float* __restrict__ Wh, float* __restrict__ wmaxsq)
{
  const int a = blockIdx.x, tid = threadIdx.x;
  float p = 0.f;
  for (int d = tid; d < H_; d += 256) {
    const float w = Wh[(size_t)a * H_ + d];
    p += w * w;
  }
  __shared__ float red[256];
  red[tid] = p; __syncthreads();
  for (int t = 128; t > 0; t >>= 1) {
    if (tid < t) red[tid] += red[tid + t];
    __syncthreads();
  }
  if (tid == 0) atomicMax((int*)wmaxsq, __float_as_int(red[0]));
}

// ================= software-pipelined f16-split MFMA GEMM =================
// C[M,N] = A @ B^T (pre-split, scaled x64; epilogue /4096 + bias).
// NPASS=3: hi*hi + lo*hi + hi*lo.  NPASS=1: hi*hi.
// Double-buffered global_load_lds: DMA(t+1) issued before compute(t), so
// the barrier drain only pays latency not covered by MFMA.
template<int ACT, int WF32, int WSPLIT, int NPASS>
__device__ __forceinline__
void gemm_body(const _Float16* __restrict__ Ahi, const _Float16* __restrict__ Alo,
               const _Float16* __restrict__ Bhi, const _Float16* __restrict__ Blo,
               const float* __restrict__ bias, float* __restrict__ C,
               _Float16* __restrict__ Chi, _Float16* __restrict__ Clo,
               int M, int N, int K, _Float16* sAf, _Float16* sBf)
{
  // layout: sAf[buf][split][128*32]
  constexpr int NSP = (NPASS == 3) ? 2 : 1;
  const int tid = threadIdx.x;
  const int lane = tid & 63, wave = tid >> 6;
  const int wx = wave & 1, wy = wave >> 1;
  const int bm = blockIdx.y * 128, bn = blockIdx.x * 128;
  const int q = lane >> 4, mr = lane & 15;

  auto sA = [&](int pb, int sp) { return sAf + (pb * NSP + sp) * (128 * 32); };
  auto sB = [&](int pb, int sp) { return sBf + (pb * NSP + sp) * (128 * 32); };

  auto stage = [&](int k0, int pb) {
#pragma unroll
    for (int t = 0; t < 2; ++t) {
      const int c = wave * 2 + t;                 // chunk 0..7 (16 rows x 32 f16)
      const int row = c * 16 + (lane >> 2);
      const int kc = (lane & 3) * 8;
      const size_t ga = (size_t)(bm + row) * K + k0 + kc;
      const size_t gb = (size_t)(bn + row) * K + k0 + kc;
      gload16(Ahi + ga, sA(pb, 0) + c * 512);
      gload16(Bhi + gb, sB(pb, 0) + c * 512);
      if constexpr (NPASS == 3) {
        gload16(Alo + ga, sA(pb, 1) + c * 512);
        gload16(Blo + gb, sB(pb, 1) + c * 512);
      }
    }
  };

  f32x4 acc[4][4];
#pragma unroll
  for (int i = 0; i < 4; ++i)
#pragma unroll
    for (int j = 0; j < 4; ++j) acc[i][j] = (f32x4)0.f;

  stage(0, 0);
  __syncthreads();

  const int T = K / 32;
  for (int t = 0; t < T; ++t) {
    const int pb = t & 1;
    if (t + 1 < T) stage((t + 1) * 32, pb ^ 1);   // in flight during compute

    f16x8 ah[4], al[4];
    const int abase = (wy * 64 + mr) * 32 + q * 8;
#pragma unroll
    for (int mi = 0; mi < 4; ++mi) {
      ah[mi] = *(const f16x8*)(sA(pb, 0) + abase + mi * 16 * 32);
      if constexpr (NPASS == 3)
        al[mi] = *(const f16x8*)(sA(pb, 1) + abase + mi * 16 * 32);
    }
    const int bbase = (wx * 64 + mr) * 32 + q * 8;
#pragma unroll
    for (int ni = 0; ni < 4; ++ni) {
      const f16x8 bh = *(const f16x8*)(sB(pb, 0) + bbase + ni * 16 * 32);
      if constexpr (NPASS == 3) {
        const f16x8 bl = *(const f16x8*)(sB(pb, 1) + bbase + ni * 16 * 32);
#pragma unroll
        for (int mi = 0; mi < 4; ++mi) {
          acc[mi][ni] = __builtin_amdgcn_mfma_f32_16x16x32_f16(ah[mi], bh, acc[mi][ni], 0, 0, 0);
          acc[mi][ni] = __builtin_amdgcn_mfma_f32_16x16x32_f16(al[mi], bh, acc[mi][ni], 0, 0, 0);
          acc[mi][ni] = __builtin_amdgcn_mfma_f32_16x16x32_f16(ah[mi], bl, acc[mi][ni], 0, 0, 0);
        }
      } else {
#pragma unroll
        for (int mi = 0; mi < 4; ++mi)
          acc[mi][ni] = __builtin_amdgcn_mfma_f32_16x16x32_f16(ah[mi], bh, acc[mi][ni], 0, 0, 0);
      }
    }
    __syncthreads();   // drains DMA(t+1) remainder + protects buf reuse
  }

  // epilogue: C/D layout col=lane&15, row=(lane>>4)*4+reg
  const float sc = 1.f / 4096.f;
#pragma unroll
  for (int ni = 0; ni < 4; ++ni) {
    const int n = bn + wx * 64 + ni * 16 + mr;
    if (n >= N) continue;
    const float bv = bias[n];
#pragma unroll
    for (int mi = 0; mi < 4; ++mi) {
      const int m0 = bm + wy * 64 + mi * 16 + q * 4;
#pragma unroll
      for (int r = 0; r < 4; ++r) {
        float v = acc[mi][ni][r] * sc + bv;
        if (ACT) v = fmaxf(v, 0.f);
        const size_t off = (size_t)(m0 + r) * N + n;
        if (WF32) C[off] = v;
        if (WSPLIT) {
          const HL s = split64(v);
          Chi[off] = s.h;
          Clo[off] = s.l;
        }
      }
    }
  }
}

template<int ACT, int WF32, int WSPLIT, int NPASS>
__global__ __launch_bounds__(256)
void gemmA(const _Float16* __restrict__ Ahi, const _Float16* __restrict__ Alo,
           const _Float16* __restrict__ Bhi, const _Float16* __restrict__ Blo,
           const float* __restrict__ bias, float* __restrict__ C,
           _Float16* __restrict__ Chi, _Float16* __restrict__ Clo,
           int M, int N, int K)
{
  constexpr int NSP = (NPASS == 3) ? 2 : 1;
  __shared__ _Float16 sAf[2 * NSP * 128 * 32];
  __shared__ _Float16 sBf[2 * NSP * 128 * 32];
  gemm_body<ACT, WF32, WSPLIT, NPASS>(Ahi, Alo, Bhi, Blo, bias, C, Chi, Clo,
                                      M, N, K, sAf, sBf);
}

// fused gi+gh: blockIdx.z selects the (A, B, bias, C) set
__global__ __launch_bounds__(256)
void gemmA_pair(const _Float16* A1h, const _Float16* A1l,
                const _Float16* B1h, const _Float16* B1l,
                const float* bias1, float* C1,
                const _Float16* A2h, const _Float16* A2l,
                const _Float16* B2h, const _Float16* B2l,
                const float* bias2, float* C2,
                int M, int N, int K)
{
  __shared__ _Float16 sAf[2 * 2 * 128 * 32];
  __shared__ _Float16 sBf[2 * 2 * 128 * 32];
  const int z = blockIdx.z;
  const _Float16* Ah = z ? A2h : A1h;
  const _Float16* Al = z ? A2l : A1l;
  const _Float16* Bh = z ? B2h : B1h;
  const _Float16* Bl = z ? B2l : B1l;
  const float* bias = z ? bias2 : bias1;
  float* C = z ? C2 : C1;
  gemm_body<0, 1, 0, 3>(Ah, Al, Bh, Bl, bias, C, nullptr, nullptr,
                        M, N, K, sAf, sBf);
}

// ---------------- split x (scaled x64) ----------------
__global__ __launch_bounds__(256)
void split4_k(const float* __restrict__ src, _Float16* __restrict__ hi,
              _Float16* __restrict__ lo, int n4)
{
  const int i = blockIdx.x * 256 + threadIdx.x;
  if (i >= n4) return;
  const float4 f = ((const float4*)src)[i];
  const HL s0 = split64(f.x), s1 = split64(f.y);
  const HL s2 = split64(f.z), s3 = split64(f.w);
  const f16x4 hv = {s0.h, s1.h, s2.h, s3.h};
  const f16x4 lv = {s0.l, s1.l, s2.l, s3.l};
  ((f16x4*)hi)[i] = hv;
  ((f16x4*)lo)[i] = lv;
}

// ---------------- mask init (+ step-0 row_zero fix) ----------------
__global__ __launch_bounds__(256)
void mask_init(const int* __restrict__ xmask, uint8_t* __restrict__ mask)
{
  const int b = blockIdx.x, tid = threadIdx.x;
  int s = 0;
  for (int a = tid; a < A_; a += 256) {
    const int m = (xmask[(size_t)b * A_ + a] != 0) ? 1 : 0;
    mask[(size_t)b * A_ + a] = (uint8_t)m;
    s += m;
  }
  __shared__ int red[256];
  red[tid] = s; __syncthreads();
  for (int t = 128; t > 0; t >>= 1) {
    if (tid < t) red[tid] += red[tid + t];
    __syncthreads();
  }
  if (tid == 0 && red[0] == 0) mask[(size_t)b * A_] = 1;
}

// ---------------- GRU elementwise + fused h split ----------------
__global__ __launch_bounds__(256)
void gru_elem(const float* __restrict__ gi, const float* __restrict__ gh,
              const float* __restrict__ bhh, float* __restrict__ h,
              _Float16* __restrict__ hh_, _Float16* __restrict__ hl_, int first)
{
  const int i = blockIdx.x * 256 + threadIdx.x;
  if (i >= B_ * H_) return;
  const int b = i / H_;
  const int d = i - b * H_;
  const float* gib = gi + (size_t)b * 3 * H_;
  const float ir = gib[d], iz = gib[H_ + d], in_ = gib[2 * H_ + d];
  float hr, hz, hn, hp;
  if (first) {            // h == 0 -> gh = b_hh exactly (saves a full GEMM)
    hr = bhh[d]; hz = bhh[H_ + d]; hn = bhh[2 * H_ + d]; hp = 0.f;
  } else {
    const float* ghb = gh + (size_t)b * 3 * H_;
    hr = ghb[d]; hz = ghb[H_ + d]; hn = ghb[2 * H_ + d]; hp = h[i];
  }
  const float r = 1.f / (1.f + expf(-(ir + hr)));
  const float z = 1.f / (1.f + expf(-(iz + hz)));
  const float n = tanhf(in_ + r * hn);
  const float hv = (1.f - z) * n + z * hp;
  h[i] = hv;
  const HL s = split64(hv);
  hh_[i] = s.h; hl_[i] = s.l;
}

// ---------------- select: approx argmax + sound exact refine ----------
__global__ __launch_bounds__(256)
void select_step(const float* __restrict__ logits, uint8_t* __restrict__ mask,
                 int* __restrict__ idxs, const float* __restrict__ cls,
                 const float* __restrict__ ae, _Float16* __restrict__ curh,
                 _Float16* __restrict__ curl, float* __restrict__ atomp,
                 const float* __restrict__ hbuf, const float* __restrict__ WhF,
                 const float* __restrict__ bh, const float* __restrict__ wmaxsq,
                 uint32_t k0, uint32_t k1, int step)
{
  const int b = blockIdx.x, tid = threadIdx.x;
  uint8_t* mrow = mask + (size_t)b * A_;
  __shared__ float hsh[H_];
  __shared__ float sv[256];
  __shared__ int   si[256];
  __shared__ int   s_list[256];
  __shared__ int   s_n;
  __shared__ int   s_sel;

  // h row -> LDS + ||h||^2
  float hp = 0.f;
  for (int d = tid; d < H_; d += 256) {
    const float v = hbuf[(size_t)b * H_ + d];
    hsh[d] = v; hp += v * v;
  }
  sv[tid] = hp; __syncthreads();
  for (int t = 128; t > 0; t >>= 1) {
    if (tid < t) sv[tid] += sv[tid + t];
    __syncthreads();
  }
  const float hn2 = sv[0];
  __syncthreads();

  // mask update
  if (step > 0) {
    const int prev = idxs[(step - 1) * B_ + b];
    if (prev == 0)
      for (int a = tid; a < A_; a += 256) mrow[a] = 0;
    __syncthreads();
    if (tid == 0) mrow[0] = 1;
  }
  if (tid == 0) s_n = 0;
  __syncthreads();

  // approx max of (logit_approx + gumbel) over allowed atoms
  const uint32_t nbase = (uint32_t)b * (uint32_t)A_;
  const float* lrow = logits + (size_t)b * A_;
  float bv = -INFINITY; int bi = A_;
  for (int a = tid; a < A_; a += 256) if (mrow[a]) {
    const float v = lrow[a] + gumbel_for(k0, k1, nbase + (uint32_t)a);
    if (v > bv) { bv = v; bi = a; }
  }
  sv[tid] = bv; si[tid] = bi; __syncthreads();
  for (int t = 128; t > 0; t >>= 1) {
    if (tid < t) {
      const float v2 = sv[tid + t]; const int i2 = si[tid + t];
      if (v2 > sv[tid] || (v2 == sv[tid] && i2 < si[tid])) { sv[tid] = v2; si[tid] = i2; }
    }
    __syncthreads();
  }
  const float amax = sv[0];
  __syncthreads();

  // error bound: |approx-exact| <= 2^-10 * ||h|| * max||w_a||  (x2 safety)
  const float delta = 2.0f * 0.0009765625f * sqrtf(hn2 * wmaxsq[0]);
  const float thr = amax - 2.f * delta;

  // collect candidates within the window
  for (int a = tid; a < A_; a += 256) if (mrow[a]) {
    const float v = lrow[a] + gumbel_for(k0, k1, nbase + (uint32_t)a);
    if (v >= thr) {
      const int p = atomicAdd(&s_n, 1);
      if (p < 256) s_list[p] = a;
    }
  }
  __syncthreads();
  const int nc = (s_n < 256) ? s_n : 256;

  // exact fp32 re-eval of candidates; argmax with lowest-index tie-break
  float best = -INFINITY; int bestA = A_;
  for (int c = 0; c < nc; ++c) {
    const int a = s_list[c];
    const float* wr = WhF + (size_t)a * H_;
    float p = 0.f;
    for (int d = tid; d < H_; d += 256) p += hsh[d] * wr[d];
    sv[tid] = p; __syncthreads();
    for (int t = 128; t > 0; t >>= 1) {
      if (tid < t) sv[tid] += sv[tid + t];
      __syncthreads();
    }
    if (tid == 0) {
      const float ev = sv[0] + bh[a] + gumbel_for(k0, k1, nbase + (uint32_t)a);
      if (ev > best || (ev == best && a < bestA)) { best = ev; bestA = a; }
    }
    __syncthreads();
  }
  if (tid == 0) {
    s_sel = bestA;
    mrow[bestA] = 0;
    idxs[step * B_ + b] = bestA;
    atomp[(size_t)b * (RL_ * A_) + (size_t)step * A_ + bestA] = 1.0f;
  }
  __syncthreads();
  const int sel = s_sel;
  const float* aerow = ae + (size_t)sel * H_;
  const float* clsr  = cls + (size_t)b * H_;
  for (int d = tid; d < H_; d += 256) {
    const float c = clsr[d] + aerow[d];
    const HL s = split64(c);
    curh[(size_t)b * H_ + d] = s.h;
    curl[(size_t)b * H_ + d] = s.l;
  }
}

// ---------------- final heads ----------------
__global__ __launch_bounds__(256)
void head_k(const int* __restrict__ idxs, const float* __restrict__ ae,
            const float* __restrict__ w_mu, const float* __restrict__ b_mu,
            const float* __restrict__ w_cov, const float* __restrict__ b_cov,
            const float* __restrict__ alpha, float* __restrict__ outf)
{
  const int b = blockIdx.x, tid = threadIdx.x;
  const int i0 = idxs[0 * B_ + b], i1 = idxs[1 * B_ + b];
  const int i2 = idxs[2 * B_ + b], i3 = idxs[3 * B_ + b];
  const float* r0 = ae + (size_t)i0 * H_;
  const float* r1 = ae + (size_t)i1 * H_;
  const float* r2 = ae + (size_t)i2 * H_;
  const float* r3 = ae + (size_t)i3 * H_;
  float pmu = 0.f, pcv = 0.f;
  for (int d = tid; d < H_; d += 256) {
    const float a = r0[d] + r1[d] + r2[d] + r3[d];
    pmu += a * w_mu[d];
    pcv += a * w_cov[d];
  }
  __shared__ float smu[256], scv[256];
  smu[tid] = pmu; scv[tid] = pcv;
  __syncthreads();
  for (int s = 128; s > 0; s >>= 1) {
    if (tid < s) { smu[tid] += smu[tid + s]; scv[tid] += scv[tid + s]; }
    __syncthreads();
  }
  if (tid == 0) {
    const float mu = 1.f / (1.f + expf(-(smu[0] + b_mu[0])));
    const float cv = 1.f / (1.f + expf(-(scv[0] + b_cov[0])));
    const float n = cv * NDATA_;
    const float inv = alpha[0] / n;
    const float pp = (mu + inv) / (1.f + 2.f * inv);
    outf[2 * b + 0] = logf(1.f - pp);
    outf[2 * b + 1] = logf(pp);
    float* cp = outf + 2 * B_ + (size_t)B_ * RL_ * A_;
    cp[2 * b + 0] = 1.f - pp;
    cp[2 * b + 1] = pp;
  }
}

// ---------------- launch ----------------
extern "C" void kernel_launch(void* const* d_in, const int* in_sizes, int n_in,
                              void* d_out, int out_size, void* d_ws, size_t ws_size,
                              hipStream_t stream)
{
  const float* x     = (const float*)d_in[0];
  const int*   xmask = (const int*)d_in[1];
  const float* W1 = (const float*)d_in[2];  const float* b1 = (const float*)d_in[3];
  const float* W2 = (const float*)d_in[4];  const float* b2 = (const float*)d_in[5];
  const float* W3 = (const float*)d_in[6];  const float* b3 = (const float*)d_in[7];
  const float* Wih = (const float*)d_in[8]; const float* bih = (const float*)d_in[9];
  const float* Whh = (const float*)d_in[10];const float* bhh = (const float*)d_in[11];
  const float* Wh = (const float*)d_in[12]; const float* bh = (const float*)d_in[13];
  const float* ae = (const float*)d_in[14];
  const float* w_mu = (const float*)d_in[15];  const float* b_mu = (const float*)d_in[16];
  const float* w_cov = (const float*)d_in[17]; const float* b_cov = (const float*)d_in[18];
  const float* alpha = (const float*)d_in[19];

  char* ws = (char*)d_ws;
  size_t off = 0;
  auto alloc = [&](size_t bytes) -> void* {
    void* p = ws + off;
    off += (bytes + 255) & ~(size_t)255;
    return p;
  };
  float* cls  = (float*)alloc((size_t)B_ * H_ * 4);
  float* hbuf = (float*)alloc((size_t)B_ * H_ * 4);
  const size_t gi_bytes = (size_t)B_ * 3 * H_ * 4;       // 18.9 MB
  const size_t lg_bytes = (size_t)B_ * A_ * 4;           // 41 MB
  const size_t region_bytes = (2 * gi_bytes > lg_bytes) ? 2 * gi_bytes : lg_bytes;
  char* region = (char*)alloc(region_bytes);             // gi+gh alias logits alias x/t splits
  float* gi = (float*)region;
  float* gh = (float*)(region + gi_bytes);
  float* logits = (float*)region;
  _Float16* xh  = (_Float16*)region;                     // MLP-phase aliases
  _Float16* xl  = xh + (size_t)B_ * DIN_;
  _Float16* t1h = xl + (size_t)B_ * DIN_;
  _Float16* t1l = t1h + (size_t)B_ * H_;
  _Float16* t2h = t1l + (size_t)B_ * H_;
  _Float16* t2l = t2h + (size_t)B_ * H_;
  uint8_t* mask = (uint8_t*)alloc((size_t)B_ * A_);
  int* idxs = (int*)alloc((size_t)RL_ * B_ * 4);
  _Float16* curh = (_Float16*)alloc((size_t)B_ * H_ * 2);  // holds cls-split at j=0
  _Float16* curl = (_Float16*)alloc((size_t)B_ * H_ * 2);
  _Float16* hh_  = (_Float16*)alloc((size_t)B_ * H_ * 2);
  _Float16* hl_  = (_Float16*)alloc((size_t)B_ * H_ * 2);
  // weight splits (per launch; ~28 MB)
  _Float16* w1h = (_Float16*)alloc((size_t)H_ * DIN_ * 2);
  _Float16* w1l = (_Float16*)alloc((size_t)H_ * DIN_ * 2);
  _Float16* w2h = (_Float16*)alloc((size_t)H_ * H_ * 2);
  _Float16* w2l = (_Float16*)alloc((size_t)H_ * H_ * 2);
  _Float16* w3h = (_Float16*)alloc((size_t)H_ * H_ * 2);
  _Float16* w3l = (_Float16*)alloc((size_t)H_ * H_ * 2);
  _Float16* wihh = (_Float16*)alloc((size_t)3 * H_ * H_ * 2);
  _Float16* wihl = (_Float16*)alloc((size_t)3 * H_ * H_ * 2);
  _Float16* whhh = (_Float16*)alloc((size_t)3 * H_ * H_ * 2);
  _Float16* whhl = (_Float16*)alloc((size_t)3 * H_ * H_ * 2);
  _Float16* whhi = (_Float16*)alloc((size_t)APAD_ * H_ * 2);  // Wh hi only (1-pass)
  float* wmaxsq = (float*)alloc(4);

  float* outf  = (float*)d_out;
  float* atomp = outf + 2 * B_;

  (void)hipMemsetAsync(d_out, 0, (size_t)out_size * sizeof(float), stream);
  (void)hipMemsetAsync(wmaxsq, 0, 4, stream);

  // one merged presplit launch for all 6 weight tensors
  PSJobs J;
  const float* srcs[6] = {W1, W2, W3, Wih, Whh, Wh};
  _Float16* his[6] = {w1h, w2h, w3h, wihh, whhh, whhi};
  _Float16* los[6] = {w1l, w2l, w3l, wihl, whhl, nullptr};
  const int Rs[6] = {H_, H_, H_, 3 * H_, 3 * H_, A_};
  const int Rpads[6] = {H_, H_, H_, 3 * H_, 3 * H_, APAD_};
  const int Ks[6] = {DIN_, H_, H_, H_, H_, H_};
  J.cum[0] = 0;
  for (int j = 0; j < 6; ++j) {
    J.src[j] = srcs[j]; J.hi[j] = his[j]; J.lo[j] = los[j];
    J.R[j] = Rs[j]; J.K[j] = Ks[j];
    J.cum[j + 1] = J.cum[j] + Rpads[j] * Ks[j] / 4;
  }
  presplit_all<<<(J.cum[6] + 255) / 256, 256, 0, stream>>>(J);

  mask_init<<<B_, 256, 0, stream>>>(xmask, mask);
  wmax_k<<<A_, 256, 0, stream>>>(Wh, wmaxsq);
  split4_k<<<(B_ * DIN_ / 4 + 255) / 256, 256, 0, stream>>>(x, xh, xl, B_ * DIN_ / 4);

  // base MLP: x -> t1 -> t2 -> cls (fp32 + split into curh/curl)
  gemmA<1, 0, 1, 3><<<dim3(H_ / 128, B_ / 128), 256, 0, stream>>>(
      xh, xl, w1h, w1l, b1, nullptr, t1h, t1l, B_, H_, DIN_);
  gemmA<1, 0, 1, 3><<<dim3(H_ / 128, B_ / 128), 256, 0, stream>>>(
      t1h, t1l, w2h, w2l, b2, nullptr, t2h, t2l, B_, H_, H_);
  gemmA<0, 1, 1, 3><<<dim3(H_ / 128, B_ / 128), 256, 0, stream>>>(
      t2h, t2l, w3h, w3l, b3, cls, curh, curl, B_, H_, H_);

  uint32_t fk0[RL_], fk1[RL_];
  for (int j = 0; j < RL_; ++j)
    threefry2x32(0u, 42u, 0u, (uint32_t)j, &fk0[j], &fk1[j]);

  for (int j = 0; j < RL_; ++j) {
    if (j == 0) {
      gemmA<0, 1, 0, 3><<<dim3(3 * H_ / 128, B_ / 128), 256, 0, stream>>>(
          curh, curl, wihh, wihl, bih, gi, nullptr, nullptr, B_, 3 * H_, H_);
    } else {
      gemmA_pair<<<dim3(3 * H_ / 128, B_ / 128, 2), 256, 0, stream>>>(
          curh, curl, wihh, wihl, bih, gi,
          hh_, hl_, whhh, whhl, bhh, gh, B_, 3 * H_, H_);
    }
    gru_elem<<<(B_ * H_ + 255) / 256, 256, 0, stream>>>(gi, gh, bhh, hbuf, hh_, hl_,
                                                        j == 0 ? 1 : 0);
    gemmA<0, 1, 0, 1><<<dim3(APAD_ / 128, B_ / 128), 256, 0, stream>>>(
        hh_, nullptr, whhi, nullptr, bh, logits, nullptr, nullptr, B_, A_, H_);
    select_step<<<B_, 256, 0, stream>>>(logits, mask, idxs, cls, ae, curh, curl,
                                        atomp, hbuf, Wh, bh, wmaxsq,
                                        fk0[j], fk1[j], j);
  }

  head_k<<<B_, 256, 0, stream>>>(idxs, ae, w_mu, b_mu, w_cov, b_cov, alpha, outf);
}

// Round 6
// 1183.760 us; speedup vs baseline: 1.0505x; 1.0505x over previous
//
#include <hip/hip_runtime.h>
#include <stdint.h>
#include <math.h>

#define B_    2048
#define DIN_  512
#define H_    768
#define G3_   2304          // 3*H
#define A_    5001
#define APAD_ 5120
#define RL_   4
#define NDATA_ 56000.0f

typedef _Float16 f16x8 __attribute__((ext_vector_type(8)));
typedef _Float16 f16x4 __attribute__((ext_vector_type(4)));
typedef float    f32x4 __attribute__((ext_vector_type(4)));

// ---------------- threefry2x32 (exact JAX semantics) ----------------
__host__ __device__ __forceinline__ void threefry2x32(
    uint32_t k0, uint32_t k1, uint32_t x0, uint32_t x1,
    uint32_t* o0, uint32_t* o1)
{
  const uint32_t ks2 = k0 ^ k1 ^ 0x1BD11BDAu;
#define TF_R(r) { x0 += x1; x1 = (x1 << (r)) | (x1 >> (32 - (r))); x1 ^= x0; }
  x0 += k0; x1 += k1;
  TF_R(13) TF_R(15) TF_R(26) TF_R(6)
  x0 += k1;  x1 += ks2 + 1u;
  TF_R(17) TF_R(29) TF_R(16) TF_R(24)
  x0 += ks2; x1 += k0 + 2u;
  TF_R(13) TF_R(15) TF_R(26) TF_R(6)
  x0 += k0;  x1 += k1 + 3u;
  TF_R(17) TF_R(29) TF_R(16) TF_R(24)
  x0 += k1;  x1 += ks2 + 4u;
  TF_R(13) TF_R(15) TF_R(26) TF_R(6)
  x0 += ks2; x1 += k0 + 5u;
#undef TF_R
  *o0 = x0; *o1 = x1;
}

__device__ __forceinline__ float gumbel_for(uint32_t k0, uint32_t k1, uint32_t n)
{
  uint32_t o0, o1;
  threefry2x32(k0, k1, 0u, n, &o0, &o1);
  const uint32_t bits = o0 ^ o1;
  const float f = __uint_as_float((bits >> 9) | 0x3f800000u);  // [1,2)
  const float minv = 1e-6f;
  const float maxv = 1.0f - 1e-6f;
  const float span = maxv - minv;
  float u = __fmul_rn(f, span);
  u = __fadd_rn(u, minv);
  u = __fsub_rn(u, span);
  u = fmaxf(minv, u);
  return -logf(-logf(u));
}

// split v*64 into f16 hi/lo
struct HL { _Float16 h, l; };
__device__ __forceinline__ HL split64(float v)
{
  HL r;
  const float s = v * 64.f;
  r.h = (_Float16)s;
  r.l = (_Float16)(s - (float)r.h);
  return r;
}

// async global->LDS, 16 B/lane; LDS dst = wave-uniform base + lane*16
__device__ __forceinline__ void gload16(const void* g, void* l)
{
  __builtin_amdgcn_global_load_lds(
      (const __attribute__((address_space(1))) void*)g,
      (__attribute__((address_space(3))) void*)l, 16, 0, 0);
}

// ---------------- merged pre-split of 7 weight tensors ----------------
struct PSJobs {
  const float* src[7];
  _Float16* hi[7];
  _Float16* lo[7];
  int R[7]; int K[7];
  int cum[8];          // cumulative float4 counts
};

__global__ __launch_bounds__(256)
void presplit_all(PSJobs J)
{
  const int g = blockIdx.x * 256 + threadIdx.x;
  if (g >= J.cum[7]) return;
  int j = 0;
  while (g >= J.cum[j + 1]) ++j;
  const int i = g - J.cum[j];
  const int K = J.K[j];
  const int e = i * 4;
  const int row = e / K;
  float4 f = make_float4(0.f, 0.f, 0.f, 0.f);
  if (row < J.R[j]) f = *(const float4*)(J.src[j] + (size_t)row * K + (e - row * K));
  const HL s0 = split64(f.x), s1 = split64(f.y);
  const HL s2 = split64(f.z), s3 = split64(f.w);
  const f16x4 hv = {s0.h, s1.h, s2.h, s3.h};
  ((f16x4*)J.hi[j])[i] = hv;
  if (J.lo[j]) {
    const f16x4 lv = {s0.l, s1.l, s2.l, s3.l};
    ((f16x4*)J.lo[j])[i] = lv;
  }
}

// ---------------- combined prep: mask init + max||Wh_a||^2 + x split ------
__global__ __launch_bounds__(256)
void prep_k(const int* __restrict__ xmask, uint8_t* __restrict__ mask,
            const float* __restrict__ Wh, float* __restrict__ wmaxsq,
            const float* __restrict__ x, _Float16* __restrict__ xh,
            _Float16* __restrict__ xl)
{
  const int blk = blockIdx.x, tid = threadIdx.x;
  __shared__ float redf[256];
  __shared__ int   redi[256];
  if (blk < B_) {                       // mask init (+ step-0 row_zero fix)
    const int b = blk;
    int s = 0;
    for (int a = tid; a < A_; a += 256) {
      const int m = (xmask[(size_t)b * A_ + a] != 0) ? 1 : 0;
      mask[(size_t)b * A_ + a] = (uint8_t)m;
      s += m;
    }
    redi[tid] = s; __syncthreads();
    for (int t = 128; t > 0; t >>= 1) {
      if (tid < t) redi[tid] += redi[tid + t];
      __syncthreads();
    }
    if (tid == 0 && redi[0] == 0) mask[(size_t)b * A_] = 1;
  } else if (blk < B_ + A_) {           // max row-norm^2 of Wh
    const int a = blk - B_;
    float p = 0.f;
    for (int d = tid; d < H_; d += 256) {
      const float w = Wh[(size_t)a * H_ + d];
      p += w * w;
    }
    redf[tid] = p; __syncthreads();
    for (int t = 128; t > 0; t >>= 1) {
      if (tid < t) redf[tid] += redf[tid + t];
      __syncthreads();
    }
    if (tid == 0) atomicMax((int*)wmaxsq, __float_as_int(redf[0]));
  } else {                              // split x
    const int i = (blk - B_ - A_) * 256 + tid;
    const int n4 = B_ * DIN_ / 4;
    if (i < n4) {
      const float4 f = ((const float4*)x)[i];
      const HL s0 = split64(f.x), s1 = split64(f.y);
      const HL s2 = split64(f.z), s3 = split64(f.w);
      const f16x4 hv = {s0.h, s1.h, s2.h, s3.h};
      const f16x4 lv = {s0.l, s1.l, s2.l, s3.l};
      ((f16x4*)xh)[i] = hv;
      ((f16x4*)xl)[i] = lv;
    }
  }
}

// ================= generic 2-job f16-split MFMA GEMM =================
// Each job: C[M,N] = A @ B^T (+bias). npass=3: hihi+lohi+hilo; npass=1: hihi.
// gum=1: add gumbel(k0,k1, m*ldc+n) to the stored value (logits+gumbel fused).
// 128x128 tile, BK=32, single-buffered, global_load_lds staging (32 KB LDS).
struct GJob {
  const _Float16 *Ah, *Al, *Bh, *Bl;
  const float* bias;
  float* C;
  _Float16 *Ch, *Cl;
  int M, N, K, ldc;     // ldc = valid/stored N (store iff n < ldc)
  int npass, act, wsplit, gum;
};
struct GArgs { GJob j[2]; int sx; uint32_t k0, k1; };

__global__ __launch_bounds__(256)
void gemm2job(GArgs P)
{
  __shared__ _Float16 sA[2][128 * 32];
  __shared__ _Float16 sB[2][128 * 32];

  const int jid = (blockIdx.x < P.sx) ? 0 : 1;
  const GJob J = P.j[jid];
  const int bxx = blockIdx.x - (jid ? P.sx : 0);
  const int bm = blockIdx.y * 128;
  if (bm >= J.M) return;
  const int bn = bxx * 128;

  const int tid = threadIdx.x;
  const int lane = tid & 63, wave = tid >> 6;
  const int wx = wave & 1, wy = wave >> 1;
  const int q = lane >> 4, mr = lane & 15;
  const int K = J.K;
  const int np3 = (J.npass == 3);

  f32x4 acc[4][4];
#pragma unroll
  for (int i = 0; i < 4; ++i)
#pragma unroll
    for (int j = 0; j < 4; ++j) acc[i][j] = (f32x4)0.f;

  for (int k0 = 0; k0 < K; k0 += 32) {
    __syncthreads();
#pragma unroll
    for (int t = 0; t < 2; ++t) {
      const int c = wave * 2 + t;                 // chunk: 16 rows x 32 f16
      const int row = c * 16 + (lane >> 2);
      const int kc = (lane & 3) * 8;
      const size_t ga = (size_t)(bm + row) * K + k0 + kc;
      const size_t gb = (size_t)(bn + row) * K + k0 + kc;
      gload16(J.Ah + ga, &sA[0][c * 512]);
      gload16(J.Bh + gb, &sB[0][c * 512]);
      if (np3) {
        gload16(J.Al + ga, &sA[1][c * 512]);
        gload16(J.Bl + gb, &sB[1][c * 512]);
      }
    }
    __syncthreads();

    f16x8 ah[4], al[4];
    const int abase = (wy * 64 + mr) * 32 + q * 8;
#pragma unroll
    for (int mi = 0; mi < 4; ++mi) {
      ah[mi] = *(const f16x8*)&sA[0][abase + mi * 16 * 32];
      if (np3) al[mi] = *(const f16x8*)&sA[1][abase + mi * 16 * 32];
    }
    const int bbase = (wx * 64 + mr) * 32 + q * 8;
    if (np3) {
#pragma unroll
      for (int ni = 0; ni < 4; ++ni) {
        const f16x8 bh = *(const f16x8*)&sB[0][bbase + ni * 16 * 32];
        const f16x8 bl = *(const f16x8*)&sB[1][bbase + ni * 16 * 32];
#pragma unroll
        for (int mi = 0; mi < 4; ++mi) {
          acc[mi][ni] = __builtin_amdgcn_mfma_f32_16x16x32_f16(ah[mi], bh, acc[mi][ni], 0, 0, 0);
          acc[mi][ni] = __builtin_amdgcn_mfma_f32_16x16x32_f16(al[mi], bh, acc[mi][ni], 0, 0, 0);
          acc[mi][ni] = __builtin_amdgcn_mfma_f32_16x16x32_f16(ah[mi], bl, acc[mi][ni], 0, 0, 0);
        }
      }
    } else {
#pragma unroll
      for (int ni = 0; ni < 4; ++ni) {
        const f16x8 bh = *(const f16x8*)&sB[0][bbase + ni * 16 * 32];
#pragma unroll
        for (int mi = 0; mi < 4; ++mi)
          acc[mi][ni] = __builtin_amdgcn_mfma_f32_16x16x32_f16(ah[mi], bh, acc[mi][ni], 0, 0, 0);
      }
    }
  }

  // epilogue: C/D layout col=lane&15, row=(lane>>4)*4+reg
  const float sc = 1.f / 4096.f;
#pragma unroll
  for (int ni = 0; ni < 4; ++ni) {
    const int n = bn + wx * 64 + ni * 16 + mr;
    if (n >= J.ldc) continue;
    const float bv = J.bias ? J.bias[n] : 0.f;
#pragma unroll
    for (int mi = 0; mi < 4; ++mi) {
      const int m0 = bm + wy * 64 + mi * 16 + q * 4;
#pragma unroll
      for (int r = 0; r < 4; ++r) {
        const int m = m0 + r;
        float v = acc[mi][ni][r] * sc + bv;
        if (J.act) v = fmaxf(v, 0.f);
        if (J.gum) v += gumbel_for(P.k0, P.k1, (uint32_t)(m * J.ldc + n));
        const size_t off = (size_t)m * J.ldc + n;
        if (J.C) J.C[off] = v;
        if (J.wsplit) {
          const HL s = split64(v);
          J.Ch[off] = s.h;
          J.Cl[off] = s.l;
        }
      }
    }
  }
}

// ---------------- GRU elementwise + fused h split ----------------
__global__ __launch_bounds__(256)
void gru_elem(const float* __restrict__ gi, const float* __restrict__ gh,
              const float* __restrict__ bhh, float* __restrict__ h,
              _Float16* __restrict__ hh_, _Float16* __restrict__ hl_, int first)
{
  const int i = blockIdx.x * 256 + threadIdx.x;
  if (i >= B_ * H_) return;
  const int b = i / H_;
  const int d = i - b * H_;
  const float* gib = gi + (size_t)b * G3_;
  const float ir = gib[d], iz = gib[H_ + d], in_ = gib[2 * H_ + d];
  float hr, hz, hn, hp;
  if (first) {            // h == 0 -> gh = b_hh exactly (saves a full GEMM)
    hr = bhh[d]; hz = bhh[H_ + d]; hn = bhh[2 * H_ + d]; hp = 0.f;
  } else {
    const float* ghb = gh + (size_t)b * G3_;
    hr = ghb[d]; hz = ghb[H_ + d]; hn = ghb[2 * H_ + d]; hp = h[i];
  }
  const float r = 1.f / (1.f + expf(-(ir + hr)));
  const float z = 1.f / (1.f + expf(-(iz + hz)));
  const float n = tanhf(in_ + r * hn);
  const float hv = (1.f - z) * n + z * hp;
  h[i] = hv;
  const HL s = split64(hv);
  hh_[i] = s.h; hl_[i] = s.l;
}

// ---------------- select: v (=approx logit + gumbel) argmax + exact refine,
//                  then gi_{j+1} = giCls + AeWih[sel] gather-add -------------
__global__ __launch_bounds__(256)
void select_step(const float* __restrict__ v, uint8_t* __restrict__ mask,
                 int* __restrict__ idxs, const float* __restrict__ giCls,
                 const float* __restrict__ AeWih, float* __restrict__ gi,
                 float* __restrict__ atomp, const float* __restrict__ hbuf,
                 const float* __restrict__ WhF, const float* __restrict__ bh,
                 const float* __restrict__ wmaxsq,
                 uint32_t k0, uint32_t k1, int step)
{
  const int b = blockIdx.x, tid = threadIdx.x;
  uint8_t* mrow = mask + (size_t)b * A_;
  __shared__ float vsh[A_];        // masked v row cache (20 KB)
  __shared__ float hsh[H_];
  __shared__ float sv[256];
  __shared__ int   si[256];
  __shared__ int   s_list[64];
  __shared__ int   s_n;
  __shared__ int   s_sel;

  // h row -> LDS + ||h||^2
  float hp = 0.f;
  for (int d = tid; d < H_; d += 256) {
    const float t = hbuf[(size_t)b * H_ + d];
    hsh[d] = t; hp += t * t;
  }
  sv[tid] = hp; __syncthreads();
  for (int t = 128; t > 0; t >>= 1) {
    if (tid < t) sv[tid] += sv[tid + t];
    __syncthreads();
  }
  const float hn2 = sv[0];
  __syncthreads();

  // mask update
  if (step > 0) {
    const int prev = idxs[(step - 1) * B_ + b];
    if (prev == 0)
      for (int a = tid; a < A_; a += 256) mrow[a] = 0;
    __syncthreads();
    if (tid == 0) mrow[0] = 1;
  }
  if (tid == 0) s_n = 0;
  __syncthreads();

  // single pass: mask-apply, cache in LDS, track max
  const float* vrow = v + (size_t)b * A_;
  float bv = -INFINITY; int bi = A_;
  for (int a = tid; a < A_; a += 256) {
    const float val = mrow[a] ? vrow[a] : -INFINITY;
    vsh[a] = val;
    if (val > bv) { bv = val; bi = a; }
  }
  sv[tid] = bv; si[tid] = bi; __syncthreads();
  for (int t = 128; t > 0; t >>= 1) {
    if (tid < t) {
      const float v2 = sv[tid + t]; const int i2 = si[tid + t];
      if (v2 > sv[tid] || (v2 == sv[tid] && i2 < si[tid])) { sv[tid] = v2; si[tid] = i2; }
    }
    __syncthreads();
  }
  const float amax = sv[0];
  __syncthreads();

  // |approx-exact| <= 2^-10 * ||h|| * max||w_a||  (x2 safety)
  const float delta = 2.0f * 0.0009765625f * sqrtf(hn2 * wmaxsq[0]);
  const float thr = amax - 2.f * delta;

  for (int a = tid; a < A_; a += 256)
    if (vsh[a] >= thr) {
      const int p = atomicAdd(&s_n, 1);
      if (p < 64) s_list[p] = a;
    }
  __syncthreads();
  const int nc = (s_n < 64) ? s_n : 64;

  // exact fp32 re-eval; argmax with lowest-index tie-break
  const uint32_t nbase = (uint32_t)b * (uint32_t)A_;
  float best = -INFINITY; int bestA = A_;
  for (int c = 0; c < nc; ++c) {
    const int a = s_list[c];
    const float* wr = WhF + (size_t)a * H_;
    float p = 0.f;
    for (int d = tid; d < H_; d += 256) p += hsh[d] * wr[d];
    sv[tid] = p; __syncthreads();
    for (int t = 128; t > 0; t >>= 1) {
      if (tid < t) sv[tid] += sv[tid + t];
      __syncthreads();
    }
    if (tid == 0) {
      const float ev = sv[0] + bh[a] + gumbel_for(k0, k1, nbase + (uint32_t)a);
      if (ev > best || (ev == best && a < bestA)) { best = ev; bestA = a; }
    }
    __syncthreads();
  }
  if (tid == 0) {
    s_sel = bestA;
    mrow[bestA] = 0;
    idxs[step * B_ + b] = bestA;
    atomp[(size_t)b * (RL_ * A_) + (size_t)step * A_ + bestA] = 1.0f;
  }
  __syncthreads();

  if (step < RL_ - 1) {
    const int sel = s_sel;
    const float* ar = AeWih + (size_t)sel * G3_;
    const float* gr = giCls + (size_t)b * G3_;
    float* go = gi + (size_t)b * G3_;
    for (int d = tid; d < G3_; d += 256) go[d] = gr[d] + ar[d];
  }
}

// ---------------- final heads ----------------
__global__ __launch_bounds__(256)
void head_k(const int* __restrict__ idxs, const float* __restrict__ ae,
            const float* __restrict__ w_mu, const float* __restrict__ b_mu,
            const float* __restrict__ w_cov, const float* __restrict__ b_cov,
            const float* __restrict__ alpha, float* __restrict__ outf)
{
  const int b = blockIdx.x, tid = threadIdx.x;
  const int i0 = idxs[0 * B_ + b], i1 = idxs[1 * B_ + b];
  const int i2 = idxs[2 * B_ + b], i3 = idxs[3 * B_ + b];
  const float* r0 = ae + (size_t)i0 * H_;
  const float* r1 = ae + (size_t)i1 * H_;
  const float* r2 = ae + (size_t)i2 * H_;
  const float* r3 = ae + (size_t)i3 * H_;
  float pmu = 0.f, pcv = 0.f;
  for (int d = tid; d < H_; d += 256) {
    const float a = r0[d] + r1[d] + r2[d] + r3[d];
    pmu += a * w_mu[d];
    pcv += a * w_cov[d];
  }
  __shared__ float smu[256], scv[256];
  smu[tid] = pmu; scv[tid] = pcv;
  __syncthreads();
  for (int s = 128; s > 0; s >>= 1) {
    if (tid < s) { smu[tid] += smu[tid + s]; scv[tid] += scv[tid + s]; }
    __syncthreads();
  }
  if (tid == 0) {
    const float mu = 1.f / (1.f + expf(-(smu[0] + b_mu[0])));
    const float cv = 1.f / (1.f + expf(-(scv[0] + b_cov[0])));
    const float n = cv * NDATA_;
    const float inv = alpha[0] / n;
    const float pp = (mu + inv) / (1.f + 2.f * inv);
    outf[2 * b + 0] = logf(1.f - pp);
    outf[2 * b + 1] = logf(pp);
    float* cp = outf + 2 * B_ + (size_t)B_ * RL_ * A_;
    cp[2 * b + 0] = 1.f - pp;
    cp[2 * b + 1] = pp;
  }
}

// ---------------- launch ----------------
extern "C" void kernel_launch(void* const* d_in, const int* in_sizes, int n_in,
                              void* d_out, int out_size, void* d_ws, size_t ws_size,
                              hipStream_t stream)
{
  const float* x     = (const float*)d_in[0];
  const int*   xmask = (const int*)d_in[1];
  const float* W1 = (const float*)d_in[2];  const float* b1 = (const float*)d_in[3];
  const float* W2 = (const float*)d_in[4];  const float* b2 = (const float*)d_in[5];
  const float* W3 = (const float*)d_in[6];  const float* b3 = (const float*)d_in[7];
  const float* Wih = (const float*)d_in[8]; const float* bih = (const float*)d_in[9];
  const float* Whh = (const float*)d_in[10];const float* bhh = (const float*)d_in[11];
  const float* Wh = (const float*)d_in[12]; const float* bh = (const float*)d_in[13];
  const float* ae = (const float*)d_in[14];
  const float* w_mu = (const float*)d_in[15];  const float* b_mu = (const float*)d_in[16];
  const float* w_cov = (const float*)d_in[17]; const float* b_cov = (const float*)d_in[18];
  const float* alpha = (const float*)d_in[19];

  char* ws = (char*)d_ws;
  size_t off = 0;
  auto alloc = [&](size_t bytes) -> void* {
    void* p = ws + off;
    off += (bytes + 255) & ~(size_t)255;
    return p;
  };
  // activations / state
  float* hbuf   = (float*)alloc((size_t)B_ * H_ * 4);
  float* giCls  = (float*)alloc((size_t)B_ * G3_ * 4);
  float* gi     = (float*)alloc((size_t)B_ * G3_ * 4);
  float* gh     = (float*)alloc((size_t)B_ * G3_ * 4);
  float* vbuf   = (float*)alloc((size_t)B_ * A_ * 4);
  float* AeWih  = (float*)alloc((size_t)APAD_ * G3_ * 4);
  uint8_t* mask = (uint8_t*)alloc((size_t)B_ * A_);
  int* idxs     = (int*)alloc((size_t)RL_ * B_ * 4);
  _Float16* hh_ = (_Float16*)alloc((size_t)B_ * H_ * 2);
  _Float16* hl_ = (_Float16*)alloc((size_t)B_ * H_ * 2);
  _Float16* clsh = (_Float16*)alloc((size_t)B_ * H_ * 2);
  _Float16* clsl = (_Float16*)alloc((size_t)B_ * H_ * 2);
  _Float16* xh  = (_Float16*)alloc((size_t)B_ * DIN_ * 2);
  _Float16* xl  = (_Float16*)alloc((size_t)B_ * DIN_ * 2);
  _Float16* t1h = (_Float16*)alloc((size_t)B_ * H_ * 2);
  _Float16* t1l = (_Float16*)alloc((size_t)B_ * H_ * 2);
  _Float16* t2h = (_Float16*)alloc((size_t)B_ * H_ * 2);
  _Float16* t2l = (_Float16*)alloc((size_t)B_ * H_ * 2);
  // weight splits
  _Float16* w1h = (_Float16*)alloc((size_t)H_ * DIN_ * 2);
  _Float16* w1l = (_Float16*)alloc((size_t)H_ * DIN_ * 2);
  _Float16* w2h = (_Float16*)alloc((size_t)H_ * H_ * 2);
  _Float16* w2l = (_Float16*)alloc((size_t)H_ * H_ * 2);
  _Float16* w3h = (_Float16*)alloc((size_t)H_ * H_ * 2);
  _Float16* w3l = (_Float16*)alloc((size_t)H_ * H_ * 2);
  _Float16* wihh = (_Float16*)alloc((size_t)G3_ * H_ * 2);
  _Float16* wihl = (_Float16*)alloc((size_t)G3_ * H_ * 2);
  _Float16* whhh = (_Float16*)alloc((size_t)G3_ * H_ * 2);
  _Float16* whhl = (_Float16*)alloc((size_t)G3_ * H_ * 2);
  _Float16* whhi = (_Float16*)alloc((size_t)APAD_ * H_ * 2);  // Wh hi (1-pass)
  _Float16* aeh  = (_Float16*)alloc((size_t)APAD_ * H_ * 2);
  _Float16* ael  = (_Float16*)alloc((size_t)APAD_ * H_ * 2);
  float* wmaxsq = (float*)alloc(4);

  float* outf  = (float*)d_out;
  float* atomp = outf + 2 * B_;

  (void)hipMemsetAsync(d_out, 0, (size_t)out_size * sizeof(float), stream);
  (void)hipMemsetAsync(wmaxsq, 0, 4, stream);

  // merged presplit: W1 W2 W3 Wih Whh Wh(hi) ae(hi+lo)
  PSJobs J;
  const float* srcs[7] = {W1, W2, W3, Wih, Whh, Wh, ae};
  _Float16* his[7] = {w1h, w2h, w3h, wihh, whhh, whhi, aeh};
  _Float16* los[7] = {w1l, w2l, w3l, wihl, whhl, nullptr, ael};
  const int Rs[7]    = {H_, H_, H_, G3_, G3_, A_, A_};
  const int Rpads[7] = {H_, H_, H_, G3_, G3_, APAD_, APAD_};
  const int Ks[7]    = {DIN_, H_, H_, H_, H_, H_, H_};
  J.cum[0] = 0;
  for (int j = 0; j < 7; ++j) {
    J.src[j] = srcs[j]; J.hi[j] = his[j]; J.lo[j] = los[j];
    J.R[j] = Rs[j]; J.K[j] = Ks[j];
    J.cum[j + 1] = J.cum[j] + Rpads[j] * Ks[j] / 4;
  }
  presplit_all<<<(J.cum[7] + 255) / 256, 256, 0, stream>>>(J);

  prep_k<<<B_ + A_ + (B_ * DIN_ / 4 + 255) / 256, 256, 0, stream>>>(
      xmask, mask, Wh, wmaxsq, x, xh, xl);

  auto mkjob = [](const _Float16* Ah, const _Float16* Al, const _Float16* Bh,
                  const _Float16* Bl, const float* bias, float* C,
                  _Float16* Ch, _Float16* Cl, int M, int N, int K, int ldc,
                  int npass, int act, int wsplit, int gum) {
    GJob g; g.Ah = Ah; g.Al = Al; g.Bh = Bh; g.Bl = Bl; g.bias = bias;
    g.C = C; g.Ch = Ch; g.Cl = Cl; g.M = M; g.N = N; g.K = K; g.ldc = ldc;
    g.npass = npass; g.act = act; g.wsplit = wsplit; g.gum = gum;
    return g;
  };

  // fused [W1 | AeWih]
  {
    GArgs P;
    P.j[0] = mkjob(xh, xl, w1h, w1l, b1, nullptr, t1h, t1l,
                   B_, H_, DIN_, H_, 3, 1, 1, 0);
    P.j[1] = mkjob(aeh, ael, wihh, wihl, nullptr, AeWih, nullptr, nullptr,
                   APAD_, G3_, H_, G3_, 3, 0, 0, 0);
    P.sx = H_ / 128; P.k0 = 0; P.k1 = 0;
    gemm2job<<<dim3(H_ / 128 + G3_ / 128, APAD_ / 128), 256, 0, stream>>>(P);
  }
  // W2, W3 (cls split only), giCls
  {
    GArgs P;
    P.j[0] = mkjob(t1h, t1l, w2h, w2l, b2, nullptr, t2h, t2l,
                   B_, H_, H_, H_, 3, 1, 1, 0);
    P.j[1] = P.j[0]; P.sx = H_ / 128; P.k0 = 0; P.k1 = 0;
    gemm2job<<<dim3(H_ / 128, B_ / 128), 256, 0, stream>>>(P);
  }
  {
    GArgs P;
    P.j[0] = mkjob(t2h, t2l, w3h, w3l, b3, nullptr, clsh, clsl,
                   B_, H_, H_, H_, 3, 0, 1, 0);
    P.j[1] = P.j[0]; P.sx = H_ / 128; P.k0 = 0; P.k1 = 0;
    gemm2job<<<dim3(H_ / 128, B_ / 128), 256, 0, stream>>>(P);
  }
  {
    GArgs P;
    P.j[0] = mkjob(clsh, clsl, wihh, wihl, bih, giCls, nullptr, nullptr,
                   B_, G3_, H_, G3_, 3, 0, 0, 0);
    P.j[1] = P.j[0]; P.sx = G3_ / 128; P.k0 = 0; P.k1 = 0;
    gemm2job<<<dim3(G3_ / 128, B_ / 128), 256, 0, stream>>>(P);
  }

  uint32_t fk0[RL_], fk1[RL_];
  for (int j = 0; j < RL_; ++j)
    threefry2x32(0u, 42u, 0u, (uint32_t)j, &fk0[j], &fk1[j]);

  // GRU step 0 (gi = giCls, h=0)
  gru_elem<<<(B_ * H_ + 255) / 256, 256, 0, stream>>>(giCls, gh, bhh, hbuf,
                                                      hh_, hl_, 1);

  for (int j = 0; j < RL_; ++j) {
    // fused [logits_j (1-pass + gumbel) | gh_{j+1} (3-pass)] — both read h_j
    GArgs P;
    P.j[0] = mkjob(hh_, nullptr, whhi, nullptr, bh, vbuf, nullptr, nullptr,
                   B_, APAD_, H_, A_, 1, 0, 0, 1);
    const int gx0 = APAD_ / 128;
    int gx = gx0;
    if (j < RL_ - 1) {
      P.j[1] = mkjob(hh_, hl_, whhh, whhl, bhh, gh, nullptr, nullptr,
                     B_, G3_, H_, G3_, 3, 0, 0, 0);
      gx += G3_ / 128;
    } else {
      P.j[1] = P.j[0];
    }
    P.sx = gx0; P.k0 = fk0[j]; P.k1 = fk1[j];
    gemm2job<<<dim3(gx, B_ / 128), 256, 0, stream>>>(P);

    select_step<<<B_, 256, 0, stream>>>(vbuf, mask, idxs, giCls, AeWih, gi,
                                        atomp, hbuf, Wh, bh, wmaxsq,
                                        fk0[j], fk1[j], j);
    if (j < RL_ - 1)
      gru_elem<<<(B_ * H_ + 255) / 256, 256, 0, stream>>>(gi, gh, bhh, hbuf,
                                                          hh_, hl_, 0);
  }

  head_k<<<B_, 256, 0, stream>>>(idxs, ae, w_mu, b_mu, w_cov, b_cov, alpha, outf);
}

// Round 7
// 1082.430 us; speedup vs baseline: 1.1488x; 1.0936x over previous
//
#include <hip/hip_runtime.h>
#include <stdint.h>
#include <math.h>

#define B_    2048
#define DIN_  512
#define H_    768
#define G3_   2304          // 3*H
#define A_    5001
#define APAD_ 5120
#define RL_   4
#define NDATA_ 56000.0f

typedef _Float16 f16x8 __attribute__((ext_vector_type(8)));
typedef _Float16 f16x4 __attribute__((ext_vector_type(4)));
typedef float    f32x4 __attribute__((ext_vector_type(4)));

// ---------------- threefry2x32 (exact JAX semantics) ----------------
__host__ __device__ __forceinline__ void threefry2x32(
    uint32_t k0, uint32_t k1, uint32_t x0, uint32_t x1,
    uint32_t* o0, uint32_t* o1)
{
  const uint32_t ks2 = k0 ^ k1 ^ 0x1BD11BDAu;
#define TF_R(r) { x0 += x1; x1 = (x1 << (r)) | (x1 >> (32 - (r))); x1 ^= x0; }
  x0 += k0; x1 += k1;
  TF_R(13) TF_R(15) TF_R(26) TF_R(6)
  x0 += k1;  x1 += ks2 + 1u;
  TF_R(17) TF_R(29) TF_R(16) TF_R(24)
  x0 += ks2; x1 += k0 + 2u;
  TF_R(13) TF_R(15) TF_R(26) TF_R(6)
  x0 += k0;  x1 += k1 + 3u;
  TF_R(17) TF_R(29) TF_R(16) TF_R(24)
  x0 += k1;  x1 += ks2 + 4u;
  TF_R(13) TF_R(15) TF_R(26) TF_R(6)
  x0 += ks2; x1 += k0 + 5u;
#undef TF_R
  *o0 = x0; *o1 = x1;
}

__device__ __forceinline__ float gumbel_for(uint32_t k0, uint32_t k1, uint32_t n)
{
  uint32_t o0, o1;
  threefry2x32(k0, k1, 0u, n, &o0, &o1);
  const uint32_t bits = o0 ^ o1;
  const float f = __uint_as_float((bits >> 9) | 0x3f800000u);  // [1,2)
  const float minv = 1e-6f;
  const float maxv = 1.0f - 1e-6f;
  const float span = maxv - minv;
  float u = __fmul_rn(f, span);
  u = __fadd_rn(u, minv);
  u = __fsub_rn(u, span);
  u = fmaxf(minv, u);
  return -logf(-logf(u));
}

// split v*64 into f16 hi/lo
struct HL { _Float16 h, l; };
__device__ __forceinline__ HL split64(float v)
{
  HL r;
  const float s = v * 64.f;
  r.h = (_Float16)s;
  r.l = (_Float16)(s - (float)r.h);
  return r;
}

// async global->LDS, 16 B/lane; LDS dst = wave-uniform base + lane*16
__device__ __forceinline__ void gload16(const void* g, void* l)
{
  __builtin_amdgcn_global_load_lds(
      (const __attribute__((address_space(1))) void*)g,
      (__attribute__((address_space(3))) void*)l, 16, 0, 0);
}

// ---------------- merged pre-split of 7 weight tensors ----------------
struct PSJobs {
  const float* src[7];
  _Float16* hi[7];
  _Float16* lo[7];
  int R[7]; int K[7];
  int cum[8];          // cumulative float4 counts
};

__global__ __launch_bounds__(256)
void presplit_all(PSJobs J)
{
  const int g = blockIdx.x * 256 + threadIdx.x;
  if (g >= J.cum[7]) return;
  int j = 0;
  while (g >= J.cum[j + 1]) ++j;
  const int i = g - J.cum[j];
  const int K = J.K[j];
  const int e = i * 4;
  const int row = e / K;
  float4 f = make_float4(0.f, 0.f, 0.f, 0.f);
  if (row < J.R[j]) f = *(const float4*)(J.src[j] + (size_t)row * K + (e - row * K));
  const HL s0 = split64(f.x), s1 = split64(f.y);
  const HL s2 = split64(f.z), s3 = split64(f.w);
  const f16x4 hv = {s0.h, s1.h, s2.h, s3.h};
  ((f16x4*)J.hi[j])[i] = hv;
  if (J.lo[j]) {
    const f16x4 lv = {s0.l, s1.l, s2.l, s3.l};
    ((f16x4*)J.lo[j])[i] = lv;
  }
}

// ---------------- combined prep: mask init + max||Wh_a||^2 + x split ------
__global__ __launch_bounds__(256)
void prep_k(const int* __restrict__ xmask, uint8_t* __restrict__ mask,
            const float* __restrict__ Wh, float* __restrict__ wmaxsq,
            const float* __restrict__ x, _Float16* __restrict__ xh,
            _Float16* __restrict__ xl)
{
  const int blk = blockIdx.x, tid = threadIdx.x;
  __shared__ float redf[256];
  __shared__ int   redi[256];
  if (blk < B_) {                       // mask init (+ step-0 row_zero fix)
    const int b = blk;
    int s = 0;
    for (int a = tid; a < A_; a += 256) {
      const int m = (xmask[(size_t)b * A_ + a] != 0) ? 1 : 0;
      mask[(size_t)b * A_ + a] = (uint8_t)m;
      s += m;
    }
    redi[tid] = s; __syncthreads();
    for (int t = 128; t > 0; t >>= 1) {
      if (tid < t) redi[tid] += redi[tid + t];
      __syncthreads();
    }
    if (tid == 0 && redi[0] == 0) mask[(size_t)b * A_] = 1;
  } else if (blk < B_ + A_) {           // max row-norm^2 of Wh
    const int a = blk - B_;
    float p = 0.f;
    for (int d = tid; d < H_; d += 256) {
      const float w = Wh[(size_t)a * H_ + d];
      p += w * w;
    }
    redf[tid] = p; __syncthreads();
    for (int t = 128; t > 0; t >>= 1) {
      if (tid < t) redf[tid] += redf[tid + t];
      __syncthreads();
    }
    if (tid == 0) atomicMax((int*)wmaxsq, __float_as_int(redf[0]));
  } else {                              // split x
    const int i = (blk - B_ - A_) * 256 + tid;
    const int n4 = B_ * DIN_ / 4;
    if (i < n4) {
      const float4 f = ((const float4*)x)[i];
      const HL s0 = split64(f.x), s1 = split64(f.y);
      const HL s2 = split64(f.z), s3 = split64(f.w);
      const f16x4 hv = {s0.h, s1.h, s2.h, s3.h};
      const f16x4 lv = {s0.l, s1.l, s2.l, s3.l};
      ((f16x4*)xh)[i] = hv;
      ((f16x4*)xl)[i] = lv;
    }
  }
}

// ================= generic 2-job f16-split MFMA GEMM =================
// Job: C[m, n0+n] = A[m,:] @ B[n0+n,:] + bias.  npass=3: hihi+lohi+hilo.
// K-loop: read frags->regs, barrier, DMA next tile into SAME buffer, MFMA.
// DMA(t+1) flies during MFMA(t); loop-top barrier drains it (covered).
struct GJob {
  const _Float16 *Ah, *Al, *Bh, *Bl;
  const float* bias;
  float* C;
  _Float16 *Ch, *Cl;
  int M, K, ldc, n0, Nv;   // store iff n_global < Nv; offset m*ldc + n_global
  int npass, act, wsplit, gum;
};
struct GArgs { GJob j[2]; int sx; uint32_t k0, k1; };

__global__ __launch_bounds__(256)
void gemm2job(GArgs P)
{
  __shared__ _Float16 sA[2][128 * 32];
  __shared__ _Float16 sB[2][128 * 32];

  const int jid = (blockIdx.x < P.sx) ? 0 : 1;
  const GJob J = P.j[jid];
  const int bxx = blockIdx.x - (jid ? P.sx : 0);
  const int bm = blockIdx.y * 128;
  if (bm >= J.M) return;
  const int bn = J.n0 + bxx * 128;

  const int tid = threadIdx.x;
  const int lane = tid & 63, wave = tid >> 6;
  const int wx = wave & 1, wy = wave >> 1;
  const int q = lane >> 4, mr = lane & 15;
  const int K = J.K;
  const int np3 = (J.npass == 3);

  auto stage = [&](int k0) {
#pragma unroll
    for (int t = 0; t < 2; ++t) {
      const int c = wave * 2 + t;                 // chunk: 16 rows x 32 f16
      const int row = c * 16 + (lane >> 2);
      const int kc = (lane & 3) * 8;
      const size_t ga = (size_t)(bm + row) * K + k0 + kc;
      const size_t gb = (size_t)(bn + row) * K + k0 + kc;
      gload16(J.Ah + ga, &sA[0][c * 512]);
      gload16(J.Bh + gb, &sB[0][c * 512]);
      if (np3) {
        gload16(J.Al + ga, &sA[1][c * 512]);
        gload16(J.Bl + gb, &sB[1][c * 512]);
      }
    }
  };

  f32x4 acc[4][4];
#pragma unroll
  for (int i = 0; i < 4; ++i)
#pragma unroll
    for (int j = 0; j < 4; ++j) acc[i][j] = (f32x4)0.f;

  stage(0);
  const int T = K / 32;
  const int abase = (wy * 64 + mr) * 32 + q * 8;
  const int bbase = (wx * 64 + mr) * 32 + q * 8;

  for (int t = 0; t < T; ++t) {
    __syncthreads();                    // DMA(t) complete for all waves
    f16x8 ah[4], al[4], bhv[4], blv[4];
#pragma unroll
    for (int mi = 0; mi < 4; ++mi) {
      ah[mi]  = *(const f16x8*)&sA[0][abase + mi * 512];
      bhv[mi] = *(const f16x8*)&sB[0][bbase + mi * 512];
    }
    if (np3) {
#pragma unroll
      for (int mi = 0; mi < 4; ++mi) {
        al[mi]  = *(const f16x8*)&sA[1][abase + mi * 512];
        blv[mi] = *(const f16x8*)&sB[1][bbase + mi * 512];
      }
    }
    __syncthreads();                    // all frag reads done -> buffer free
    if (t + 1 < T) stage((t + 1) * 32); // DMA flies during MFMA below

    if (np3) {
#pragma unroll
      for (int ni = 0; ni < 4; ++ni)
#pragma unroll
        for (int mi = 0; mi < 4; ++mi) {
          acc[mi][ni] = __builtin_amdgcn_mfma_f32_16x16x32_f16(ah[mi], bhv[ni], acc[mi][ni], 0, 0, 0);
          acc[mi][ni] = __builtin_amdgcn_mfma_f32_16x16x32_f16(al[mi], bhv[ni], acc[mi][ni], 0, 0, 0);
          acc[mi][ni] = __builtin_amdgcn_mfma_f32_16x16x32_f16(ah[mi], blv[ni], acc[mi][ni], 0, 0, 0);
        }
    } else {
#pragma unroll
      for (int ni = 0; ni < 4; ++ni)
#pragma unroll
        for (int mi = 0; mi < 4; ++mi)
          acc[mi][ni] = __builtin_amdgcn_mfma_f32_16x16x32_f16(ah[mi], bhv[ni], acc[mi][ni], 0, 0, 0);
    }
  }

  // epilogue: C/D layout col=lane&15, row=(lane>>4)*4+reg
  const float sc = 1.f / 4096.f;
#pragma unroll
  for (int ni = 0; ni < 4; ++ni) {
    const int n = bn + wx * 64 + ni * 16 + mr;
    if (n >= J.Nv) continue;
    const float bv = J.bias ? J.bias[n] : 0.f;
#pragma unroll
    for (int mi = 0; mi < 4; ++mi) {
      const int m0 = bm + wy * 64 + mi * 16 + q * 4;
#pragma unroll
      for (int r = 0; r < 4; ++r) {
        const int m = m0 + r;
        float v = acc[mi][ni][r] * sc + bv;
        if (J.act) v = fmaxf(v, 0.f);
        if (J.gum) v += gumbel_for(P.k0, P.k1, (uint32_t)(m * J.ldc + n));
        const size_t off = (size_t)m * J.ldc + n;
        if (J.C) J.C[off] = v;
        if (J.wsplit) {
          const HL s = split64(v);
          J.Ch[off] = s.h;
          J.Cl[off] = s.l;
        }
      }
    }
  }
}

// ---------------- GRU elementwise (step 0 only) + fused h split ----------
__global__ __launch_bounds__(256)
void gru_elem(const float* __restrict__ gi, const float* __restrict__ bhh,
              float* __restrict__ h, _Float16* __restrict__ hh_,
              _Float16* __restrict__ hl_)
{
  const int i = blockIdx.x * 256 + threadIdx.x;
  if (i >= B_ * H_) return;
  const int b = i / H_;
  const int d = i - b * H_;
  const float* gib = gi + (size_t)b * G3_;
  const float ir = gib[d], iz = gib[H_ + d], in_ = gib[2 * H_ + d];
  const float hr = bhh[d], hz = bhh[H_ + d], hn = bhh[2 * H_ + d];
  const float r = 1.f / (1.f + expf(-(ir + hr)));
  const float z = 1.f / (1.f + expf(-(iz + hz)));
  const float n = tanhf(in_ + r * hn);
  const float hv = (1.f - z) * n;      // h_prev = 0
  h[i] = hv;
  const HL s = split64(hv);
  hh_[i] = s.h; hl_[i] = s.l;
}

// ---------------- select + fused GRU for the next step --------------------
__global__ __launch_bounds__(256)
void select_step(const float* __restrict__ v, uint8_t* __restrict__ mask,
                 int* __restrict__ idxs, const float* __restrict__ giCls,
                 const float* __restrict__ AeWih, float* __restrict__ atomp,
                 float* __restrict__ hbuf, const float* __restrict__ WhF,
                 const float* __restrict__ bh, const float* __restrict__ wmaxsq,
                 const float* __restrict__ gh, const float* __restrict__ bhh,
                 _Float16* __restrict__ hh_, _Float16* __restrict__ hl_,
                 uint32_t k0, uint32_t k1, int step)
{
  const int b = blockIdx.x, tid = threadIdx.x;
  uint8_t* mrow = mask + (size_t)b * A_;
  __shared__ float vsh[A_];        // masked v row cache (20 KB)
  __shared__ float hsh[H_];
  __shared__ float gish[G3_];
  __shared__ float sv[256];
  __shared__ int   si[256];
  __shared__ int   s_list[64];
  __shared__ int   s_n;
  __shared__ int   s_sel;

  // h_j row -> LDS + ||h||^2
  float hp = 0.f;
  for (int d = tid; d < H_; d += 256) {
    const float t = hbuf[(size_t)b * H_ + d];
    hsh[d] = t; hp += t * t;
  }
  sv[tid] = hp; __syncthreads();
  for (int t = 128; t > 0; t >>= 1) {
    if (tid < t) sv[tid] += sv[tid + t];
    __syncthreads();
  }
  const float hn2 = sv[0];
  __syncthreads();

  // mask update
  if (step > 0) {
    const int prev = idxs[(step - 1) * B_ + b];
    if (prev == 0)
      for (int a = tid; a < A_; a += 256) mrow[a] = 0;
    __syncthreads();
    if (tid == 0) mrow[0] = 1;
  }
  if (tid == 0) s_n = 0;
  __syncthreads();

  // single pass: mask-apply, cache in LDS, track max
  const float* vrow = v + (size_t)b * A_;
  float bv = -INFINITY; int bi = A_;
  for (int a = tid; a < A_; a += 256) {
    const float val = mrow[a] ? vrow[a] : -INFINITY;
    vsh[a] = val;
    if (val > bv) { bv = val; bi = a; }
  }
  sv[tid] = bv; si[tid] = bi; __syncthreads();
  for (int t = 128; t > 0; t >>= 1) {
    if (tid < t) {
      const float v2 = sv[tid + t]; const int i2 = si[tid + t];
      if (v2 > sv[tid] || (v2 == sv[tid] && i2 < si[tid])) { sv[tid] = v2; si[tid] = i2; }
    }
    __syncthreads();
  }
  const float amax = sv[0];
  __syncthreads();

  // |approx-exact| <= 2^-10 * ||h|| * max||w_a||  (x2 safety)
  const float delta = 2.0f * 0.0009765625f * sqrtf(hn2 * wmaxsq[0]);
  const float thr = amax - 2.f * delta;

  for (int a = tid; a < A_; a += 256)
    if (vsh[a] >= thr) {
      const int p = atomicAdd(&s_n, 1);
      if (p < 64) s_list[p] = a;
    }
  __syncthreads();
  const int nc = (s_n < 64) ? s_n : 64;

  // exact fp32 re-eval; argmax with lowest-index tie-break
  const uint32_t nbase = (uint32_t)b * (uint32_t)A_;
  float best = -INFINITY; int bestA = A_;
  for (int c = 0; c < nc; ++c) {
    const int a = s_list[c];
    const float* wr = WhF + (size_t)a * H_;
    float p = 0.f;
    for (int d = tid; d < H_; d += 256) p += hsh[d] * wr[d];
    sv[tid] = p; __syncthreads();
    for (int t = 128; t > 0; t >>= 1) {
      if (tid < t) sv[tid] += sv[tid + t];
      __syncthreads();
    }
    if (tid == 0) {
      const float ev = sv[0] + bh[a] + gumbel_for(k0, k1, nbase + (uint32_t)a);
      if (ev > best || (ev == best && a < bestA)) { best = ev; bestA = a; }
    }
    __syncthreads();
  }
  if (tid == 0) {
    s_sel = bestA;
    mrow[bestA] = 0;
    idxs[step * B_ + b] = bestA;
    atomp[(size_t)b * (RL_ * A_) + (size_t)step * A_ + bestA] = 1.0f;
  }
  __syncthreads();

  if (step < RL_ - 1) {
    // gi_{j+1} row = giCls + AeWih[sel]  (LDS), then fused GRU -> h_{j+1}
    const int sel = s_sel;
    const float* ar = AeWih + (size_t)sel * G3_;
    const float* gr = giCls + (size_t)b * G3_;
    for (int d = tid; d < G3_; d += 256) gish[d] = gr[d] + ar[d];
    __syncthreads();
    const float* ghb = gh + (size_t)b * G3_;
    for (int d = tid; d < H_; d += 256) {
      const float r = 1.f / (1.f + expf(-(gish[d] + ghb[d])));
      const float z = 1.f / (1.f + expf(-(gish[H_ + d] + ghb[H_ + d])));
      const float n = tanhf(gish[2 * H_ + d] + r * ghb[2 * H_ + d]);
      const float hv = (1.f - z) * n + z * hsh[d];
      hbuf[(size_t)b * H_ + d] = hv;
      const HL s = split64(hv);
      hh_[(size_t)b * H_ + d] = s.h;
      hl_[(size_t)b * H_ + d] = s.l;
    }
  }
}

// ---------------- final heads ----------------
__global__ __launch_bounds__(256)
void head_k(const int* __restrict__ idxs, const float* __restrict__ ae,
            const float* __restrict__ w_mu, const float* __restrict__ b_mu,
            const float* __restrict__ w_cov, const float* __restrict__ b_cov,
            const float* __restrict__ alpha, float* __restrict__ outf)
{
  const int b = blockIdx.x, tid = threadIdx.x;
  const int i0 = idxs[0 * B_ + b], i1 = idxs[1 * B_ + b];
  const int i2 = idxs[2 * B_ + b], i3 = idxs[3 * B_ + b];
  const float* r0 = ae + (size_t)i0 * H_;
  const float* r1 = ae + (size_t)i1 * H_;
  const float* r2 = ae + (size_t)i2 * H_;
  const float* r3 = ae + (size_t)i3 * H_;
  float pmu = 0.f, pcv = 0.f;
  for (int d = tid; d < H_; d += 256) {
    const float a = r0[d] + r1[d] + r2[d] + r3[d];
    pmu += a * w_mu[d];
    pcv += a * w_cov[d];
  }
  __shared__ float smu[256], scv[256];
  smu[tid] = pmu; scv[tid] = pcv;
  __syncthreads();
  for (int s = 128; s > 0; s >>= 1) {
    if (tid < s) { smu[tid] += smu[tid + s]; scv[tid] += scv[tid + s]; }
    __syncthreads();
  }
  if (tid == 0) {
    const float mu = 1.f / (1.f + expf(-(smu[0] + b_mu[0])));
    const float cv = 1.f / (1.f + expf(-(scv[0] + b_cov[0])));
    const float n = cv * NDATA_;
    const float inv = alpha[0] / n;
    const float pp = (mu + inv) / (1.f + 2.f * inv);
    outf[2 * b + 0] = logf(1.f - pp);
    outf[2 * b + 1] = logf(pp);
    float* cp = outf + 2 * B_ + (size_t)B_ * RL_ * A_;
    cp[2 * b + 0] = 1.f - pp;
    cp[2 * b + 1] = pp;
  }
}

// ---------------- launch ----------------
extern "C" void kernel_launch(void* const* d_in, const int* in_sizes, int n_in,
                              void* d_out, int out_size, void* d_ws, size_t ws_size,
                              hipStream_t stream)
{
  const float* x     = (const float*)d_in[0];
  const int*   xmask = (const int*)d_in[1];
  const float* W1 = (const float*)d_in[2];  const float* b1 = (const float*)d_in[3];
  const float* W2 = (const float*)d_in[4];  const float* b2 = (const float*)d_in[5];
  const float* W3 = (const float*)d_in[6];  const float* b3 = (const float*)d_in[7];
  const float* Wih = (const float*)d_in[8]; const float* bih = (const float*)d_in[9];
  const float* Whh = (const float*)d_in[10];const float* bhh = (const float*)d_in[11];
  const float* Wh = (const float*)d_in[12]; const float* bh = (const float*)d_in[13];
  const float* ae = (const float*)d_in[14];
  const float* w_mu = (const float*)d_in[15];  const float* b_mu = (const float*)d_in[16];
  const float* w_cov = (const float*)d_in[17]; const float* b_cov = (const float*)d_in[18];
  const float* alpha = (const float*)d_in[19];

  char* ws = (char*)d_ws;
  size_t off = 0;
  auto alloc = [&](size_t bytes) -> void* {
    void* p = ws + off;
    off += (bytes + 255) & ~(size_t)255;
    return p;
  };
  float* hbuf   = (float*)alloc((size_t)B_ * H_ * 4);
  float* giCls  = (float*)alloc((size_t)B_ * G3_ * 4);
  float* gh     = (float*)alloc((size_t)B_ * G3_ * 4);
  float* vbuf   = (float*)alloc((size_t)B_ * A_ * 4);
  float* AeWih  = (float*)alloc((size_t)APAD_ * G3_ * 4);
  uint8_t* mask = (uint8_t*)alloc((size_t)B_ * A_);
  int* idxs     = (int*)alloc((size_t)RL_ * B_ * 4);
  _Float16* hh_ = (_Float16*)alloc((size_t)B_ * H_ * 2);
  _Float16* hl_ = (_Float16*)alloc((size_t)B_ * H_ * 2);
  _Float16* clsh = (_Float16*)alloc((size_t)B_ * H_ * 2);
  _Float16* clsl = (_Float16*)alloc((size_t)B_ * H_ * 2);
  _Float16* xh  = (_Float16*)alloc((size_t)B_ * DIN_ * 2);
  _Float16* xl  = (_Float16*)alloc((size_t)B_ * DIN_ * 2);
  _Float16* t1h = (_Float16*)alloc((size_t)B_ * H_ * 2);
  _Float16* t1l = (_Float16*)alloc((size_t)B_ * H_ * 2);
  _Float16* t2h = (_Float16*)alloc((size_t)B_ * H_ * 2);
  _Float16* t2l = (_Float16*)alloc((size_t)B_ * H_ * 2);
  _Float16* w1h = (_Float16*)alloc((size_t)H_ * DIN_ * 2);
  _Float16* w1l = (_Float16*)alloc((size_t)H_ * DIN_ * 2);
  _Float16* w2h = (_Float16*)alloc((size_t)H_ * H_ * 2);
  _Float16* w2l = (_Float16*)alloc((size_t)H_ * H_ * 2);
  _Float16* w3h = (_Float16*)alloc((size_t)H_ * H_ * 2);
  _Float16* w3l = (_Float16*)alloc((size_t)H_ * H_ * 2);
  _Float16* wihh = (_Float16*)alloc((size_t)G3_ * H_ * 2);
  _Float16* wihl = (_Float16*)alloc((size_t)G3_ * H_ * 2);
  _Float16* whhh = (_Float16*)alloc((size_t)G3_ * H_ * 2);
  _Float16* whhl = (_Float16*)alloc((size_t)G3_ * H_ * 2);
  _Float16* whhi = (_Float16*)alloc((size_t)APAD_ * H_ * 2);  // Wh hi (1-pass)
  _Float16* aeh  = (_Float16*)alloc((size_t)APAD_ * H_ * 2);
  _Float16* ael  = (_Float16*)alloc((size_t)APAD_ * H_ * 2);
  float* wmaxsq = (float*)alloc(4);

  float* outf  = (float*)d_out;
  float* atomp = outf + 2 * B_;

  (void)hipMemsetAsync(d_out, 0, (size_t)out_size * sizeof(float), stream);
  (void)hipMemsetAsync(wmaxsq, 0, 4, stream);

  // merged presplit: W1 W2 W3 Wih Whh Wh(hi) ae(hi+lo)
  PSJobs J;
  const float* srcs[7] = {W1, W2, W3, Wih, Whh, Wh, ae};
  _Float16* his[7] = {w1h, w2h, w3h, wihh, whhh, whhi, aeh};
  _Float16* los[7] = {w1l, w2l, w3l, wihl, whhl, nullptr, ael};
  const int Rs[7]    = {H_, H_, H_, G3_, G3_, A_, A_};
  const int Rpads[7] = {H_, H_, H_, G3_, G3_, APAD_, APAD_};
  const int Ks[7]    = {DIN_, H_, H_, H_, H_, H_, H_};
  J.cum[0] = 0;
  for (int j = 0; j < 7; ++j) {
    J.src[j] = srcs[j]; J.hi[j] = his[j]; J.lo[j] = los[j];
    J.R[j] = Rs[j]; J.K[j] = Ks[j];
    J.cum[j + 1] = J.cum[j] + Rpads[j] * Ks[j] / 4;
  }
  presplit_all<<<(J.cum[7] + 255) / 256, 256, 0, stream>>>(J);

  prep_k<<<B_ + A_ + (B_ * DIN_ / 4 + 255) / 256, 256, 0, stream>>>(
      xmask, mask, Wh, wmaxsq, x, xh, xl);

  auto mkjob = [](const _Float16* Ah, const _Float16* Al, const _Float16* Bh,
                  const _Float16* Bl, const float* bias, float* C,
                  _Float16* Ch, _Float16* Cl, int M, int K, int ldc,
                  int n0, int Nv, int npass, int act, int wsplit, int gum) {
    GJob g; g.Ah = Ah; g.Al = Al; g.Bh = Bh; g.Bl = Bl; g.bias = bias;
    g.C = C; g.Ch = Ch; g.Cl = Cl; g.M = M; g.K = K; g.ldc = ldc;
    g.n0 = n0; g.Nv = Nv; g.npass = npass; g.act = act; g.wsplit = wsplit;
    g.gum = gum;
    return g;
  };
  auto aejob = [&](int t0, int nt) {   // AeWih column-chunk job
    return mkjob(aeh, ael, wihh, wihl, nullptr, AeWih, nullptr, nullptr,
                 APAD_, H_, G3_, t0 * 128, G3_, 3, 0, 0, 0);
    (void)nt;
  };

  // MLP chain with AeWih column chunks (5,5,4,4 tiles) as concurrent filler
  {
    GArgs P;
    P.j[0] = mkjob(xh, xl, w1h, w1l, b1, nullptr, t1h, t1l,
                   B_, DIN_, H_, 0, H_, 3, 1, 1, 0);
    P.j[1] = aejob(0, 5);
    P.sx = H_ / 128; P.k0 = 0; P.k1 = 0;
    gemm2job<<<dim3(H_ / 128 + 5, APAD_ / 128), 256, 0, stream>>>(P);
  }
  {
    GArgs P;
    P.j[0] = mkjob(t1h, t1l, w2h, w2l, b2, nullptr, t2h, t2l,
                   B_, H_, H_, 0, H_, 3, 1, 1, 0);
    P.j[1] = aejob(5, 5);
    P.sx = H_ / 128; P.k0 = 0; P.k1 = 0;
    gemm2job<<<dim3(H_ / 128 + 5, APAD_ / 128), 256, 0, stream>>>(P);
  }
  {
    GArgs P;
    P.j[0] = mkjob(t2h, t2l, w3h, w3l, b3, nullptr, clsh, clsl,
                   B_, H_, H_, 0, H_, 3, 0, 1, 0);
    P.j[1] = aejob(10, 4);
    P.sx = H_ / 128; P.k0 = 0; P.k1 = 0;
    gemm2job<<<dim3(H_ / 128 + 4, APAD_ / 128), 256, 0, stream>>>(P);
  }
  {
    GArgs P;
    P.j[0] = mkjob(clsh, clsl, wihh, wihl, bih, giCls, nullptr, nullptr,
                   B_, H_, G3_, 0, G3_, 3, 0, 0, 0);
    P.j[1] = aejob(14, 4);
    P.sx = G3_ / 128; P.k0 = 0; P.k1 = 0;
    gemm2job<<<dim3(G3_ / 128 + 4, APAD_ / 128), 256, 0, stream>>>(P);
  }

  uint32_t fk0[RL_], fk1[RL_];
  for (int j = 0; j < RL_; ++j)
    threefry2x32(0u, 42u, 0u, (uint32_t)j, &fk0[j], &fk1[j]);

  // GRU step 0 (gi = giCls, h = 0)
  gru_elem<<<(B_ * H_ + 255) / 256, 256, 0, stream>>>(giCls, bhh, hbuf, hh_, hl_);

  for (int j = 0; j < RL_; ++j) {
    // fused [logits_j (1-pass + gumbel) | gh_{j+1} (3-pass)] — both read h_j
    GArgs P;
    P.j[0] = mkjob(hh_, nullptr, whhi, nullptr, bh, vbuf, nullptr, nullptr,
                   B_, H_, A_, 0, A_, 1, 0, 0, 1);
    const int gx0 = APAD_ / 128;
    int gx = gx0;
    if (j < RL_ - 1) {
      P.j[1] = mkjob(hh_, hl_, whhh, whhl, bhh, gh, nullptr, nullptr,
                     B_, H_, G3_, 0, G3_, 3, 0, 0, 0);
      gx += G3_ / 128;
    } else {
      P.j[1] = P.j[0];
    }
    P.sx = gx0; P.k0 = fk0[j]; P.k1 = fk1[j];
    gemm2job<<<dim3(gx, B_ / 128), 256, 0, stream>>>(P);

    select_step<<<B_, 256, 0, stream>>>(vbuf, mask, idxs, giCls, AeWih, atomp,
                                        hbuf, Wh, bh, wmaxsq, gh, bhh, hh_, hl_,
                                        fk0[j], fk1[j], j);
  }

  head_k<<<B_, 256, 0, stream>>>(idxs, ae, w_mu, b_mu, w_cov, b_cov, alpha, outf);
}